// Round 2
// baseline (205.763 us; speedup 1.0000x reference)
//
#include <hip/hip_runtime.h>
#include <hip/hip_bf16.h>

#define N_NODES 50000
#define N_EDGES 800000
#define HEADS   4
#define NEG_SLOPE 0.2f
#define SB      256
#define NB      ((N_NODES + SB - 1) / SB)   // 196 blocks for cnt-zeroing
#define CAP     64                    // bucket capacity; P(deg>64)~1e-18/node
#define NT      ((N_NODES + 63) / 64)       // 782 row blocks
#define NSC     782                   // extra scatter-only blocks
#define EPB     512                   // edges per block (uniform split)
#define INV_LN2 1.44269504088896340736f

typedef __attribute__((ext_vector_type(8))) _Float16 half8;  // 8 f16 (4 VGPRs)
typedef __attribute__((ext_vector_type(4))) float f32x4;     // MFMA acc
typedef __attribute__((ext_vector_type(8))) unsigned short u16x8; // 16B of f16 bits

template <typename T> __device__ __forceinline__ float cvt(T v);
template <> __device__ __forceinline__ float cvt<float>(float v) { return v; }
template <> __device__ __forceinline__ float cvt<__hip_bfloat16>(__hip_bfloat16 v) {
    return __bfloat162float(v);
}
__device__ __forceinline__ unsigned short f2h(float f) {     // f32 -> f16 bits (RNE)
    _Float16 h = (_Float16)f;
    return __builtin_bit_cast(unsigned short, h);
}
__device__ __forceinline__ float hbits(unsigned short u) {   // f16 bits -> f32
    return (float)__builtin_bit_cast(_Float16, u);           // folds into v_fma_mix
}
__device__ __forceinline__ int probe_fp32(const unsigned* xw) {
    int sane = 0;
    for (int j = 0; j < 64; ++j) {
        unsigned e = (xw[j] >> 7) & 0xFF;    // exponent of low half viewed as bf16
        sane += (e >= 90 && e <= 141);
    }
    return sane < 32;                        // junk low halves => fp32 buffer
}
__device__ __forceinline__ float loadW(int isf32, const void* W, int idx) {
    return isf32 ? ((const float*)W)[idx]
                 : cvt<__hip_bfloat16>(((const __hip_bfloat16*)W)[idx]);
}

// load 8 contiguous elems as f16, vectorized (b128 loads)
template <typename T>
__device__ __forceinline__ void load8_f16(const T* p, _Float16* dst);
template <>
__device__ __forceinline__ void load8_f16<float>(const float* p, _Float16* dst) {
    float4 a = *(const float4*)p;            // 32B-aligned (offsets are 8-float mult.)
    float4 b = *(const float4*)(p + 4);
    dst[0] = (_Float16)a.x; dst[1] = (_Float16)a.y;
    dst[2] = (_Float16)a.z; dst[3] = (_Float16)a.w;
    dst[4] = (_Float16)b.x; dst[5] = (_Float16)b.y;
    dst[6] = (_Float16)b.z; dst[7] = (_Float16)b.w;
}
template <>
__device__ __forceinline__ void load8_f16<__hip_bfloat16>(const __hip_bfloat16* p,
                                                          _Float16* dst) {
    uint4 a = *(const uint4*)p;              // 8 bf16 = 16B
    const unsigned short* u = (const unsigned short*)&a;
#pragma unroll
    for (int j = 0; j < 8; ++j)
        dst[j] = (_Float16)__uint_as_float(((unsigned)u[j]) << 16);
}

// ------------- fused init: zero cnt + probes + pack Batt (att fold) + Bpost --
// flags[0]: edge_index is int64. flags[1]: float inputs are fp32.
// Blocks 0..NB-1: zero cnt (+ block 0 publishes probes).
// Block NB: att-fold Batt = (W @ a)/ln2 in MFMA-B layout (64K x 8N, K=64).
// Blocks NB+1..NB+4: Bpost = Wstack[256,64]/4 in MFMA-B layout (8 kt x 4 nt),
// where Wstack[h*64+k, c] = W[k, h*64+c]  (post-aggregation transform; the
// 1/HEADS mean is folded in). B layout (HW-verified): within one K=32 MFMA,
// value(l,j) = B[k=(l>>4)*8+j][n=l&15].
__global__ __launch_bounds__(256) void k_init(const unsigned* __restrict__ xw,
                                              const int* __restrict__ ei,
                                              const void* __restrict__ W,
                                              const void* __restrict__ att_src,
                                              const void* __restrict__ att_dst,
                                              int* __restrict__ cnt,
                                              int* __restrict__ flags,
                                              unsigned short* __restrict__ Batt,
                                              unsigned short* __restrict__ Bpost) {
    __shared__ float waS[256], waD[256];
    __shared__ int f32sh;
    if (blockIdx.x < NB) {
        int i = blockIdx.x * blockDim.x + threadIdx.x;
        if (i < N_NODES) cnt[i] = 0;
        if (blockIdx.x == 0 && threadIdx.x == 0) {
            int all0 = 1;
            for (int j = 1; j < 64; j += 2) all0 &= (ei[j] == 0);
            flags[0] = all0;
            flags[1] = probe_fp32(xw);
        }
        return;
    }
    const int pb = blockIdx.x - NB;          // 0 = att fold, 1..4 = Bpost
    if (threadIdx.x == 0) f32sh = probe_fp32(xw);   // local probe (race-free)
    __syncthreads();
    const int isf32 = f32sh;
    if (pb == 0) {
        int t = threadIdx.x, k = t >> 2, h = t & 3;
        float s = 0.f, d = 0.f;
        for (int c = 0; c < 64; ++c) {
            float w = loadW(isf32, W, k * 256 + h * 64 + c);
            float as = isf32 ? ((const float*)att_src)[h * 64 + c]
                             : cvt<__hip_bfloat16>(((const __hip_bfloat16*)att_src)[h * 64 + c]);
            float ad = isf32 ? ((const float*)att_dst)[h * 64 + c]
                             : cvt<__hip_bfloat16>(((const __hip_bfloat16*)att_dst)[h * 64 + c]);
            s = fmaf(w, as, s);
            d = fmaf(w, ad, d);
        }
        waS[t] = s * INV_LN2;
        waD[t] = d * INV_LN2;
        __syncthreads();
        if (threadIdx.x < 128) {
            int r = threadIdx.x;             // r = q*64 + l, q = K-half
            int q = (r >> 6) & 1, l = r & 63, n = l & 15;
            int kbase = q * 32 + ((l >> 4) & 3) * 8;
#pragma unroll
            for (int j = 0; j < 8; ++j) {
                int kk = kbase + j;
                float v = (n < 4) ? waS[kk * 4 + n]
                        : (n < 8) ? waD[kk * 4 + (n - 4)] : 0.f;
                Batt[r * 8 + j] = f2h(v);
            }
        }
    } else {
        // Bpost: tile t = kt*4+nt (t = 0..31); this block packs 8 tiles.
        const int sub = threadIdx.x >> 5, s = threadIdx.x & 31;
        const int t = (pb - 1) * 8 + sub;
        const int kt = t >> 2, nt = t & 3;
#pragma unroll
        for (int e = 0; e < 16; ++e) {
            int idx = s * 16 + e;            // 0..511 within tile
            int l = idx >> 3, j = idx & 7;
            int rs = kt * 32 + ((l >> 4) & 3) * 8 + j;   // row of Wstack (0..255)
            int h = rs >> 6, k_in = rs & 63;
            int c = nt * 16 + (l & 15);
            Bpost[t * 512 + l * 8 + j] =
                f2h(loadW(isf32, W, k_in * 256 + h * 64 + c) * 0.25f);
        }
    }
}

// ---------------- logits + x->f16 copy body (row blocks of k_mid) ------------
// Block = 64 rows, 4 waves; wave w: rows 16w..16w+15; single n-tile (Batt).
// C layout (HW-verified): col=lane&15, row=quad*4+reg. Cols 0..3 = a_src heads,
// 4..7 = a_dst heads (1/ln2-scaled) -> direct fp32 global writes.
template <typename T>
__device__ __forceinline__ void row_body(const T* __restrict__ x,
                                         const unsigned short* __restrict__ Batt,
                                         unsigned short* __restrict__ x16,
                                         float* __restrict__ a_src,
                                         float* __restrict__ a_dst) {
    const int tid = threadIdx.x;
    const int wav = tid >> 6, lane = tid & 63;
    const int quad = lane >> 4, r15 = lane & 15;
    const int m0 = blockIdx.x * 64;
    int gr = m0 + wav * 16 + r15;               // this lane's A row (m = lane&15)
    if (gr >= N_NODES) gr = N_NODES - 1;        // clamp; stores guarded
    half8 afrag[2];
#pragma unroll
    for (int q = 0; q < 2; ++q) {
        _Float16 tmp[8];
        load8_f16<T>(x + (size_t)gr * 64 + q * 32 + quad * 8, tmp);
#pragma unroll
        for (int j = 0; j < 8; ++j) afrag[q][j] = tmp[j];
    }
    f32x4 acc = (f32x4){0.f, 0.f, 0.f, 0.f};
    const half8* bp = (const half8*)Batt;
    acc = __builtin_amdgcn_mfma_f32_16x16x32_f16(afrag[0], bp[lane], acc, 0, 0, 0);
    acc = __builtin_amdgcn_mfma_f32_16x16x32_f16(afrag[1], bp[64 + lane], acc, 0, 0, 0);
    if (r15 < 8) {
#pragma unroll
        for (int r = 0; r < 4; ++r) {
            int grow = m0 + wav * 16 + quad * 4 + r;
            if (grow < N_NODES) {
                if (r15 < 4) a_src[grow * HEADS + r15]       = acc[r];
                else         a_dst[grow * HEADS + (r15 - 4)] = acc[r];
            }
        }
    }
    // ---- f16 copy of x (gather source for k_agg): row = tid>>2, 16 dims ----
    {
        int row = m0 + (tid >> 2), seg = tid & 3;
        if (row < N_NODES) {
            _Float16 tmp[16];
            load8_f16<T>(x + (size_t)row * 64 + seg * 16, tmp);
            load8_f16<T>(x + (size_t)row * 64 + seg * 16 + 8, tmp + 8);
            *(u16x8*)(x16 + (size_t)row * 64 + seg * 16)     = *(const u16x8*)tmp;
            *(u16x8*)(x16 + (size_t)row * 64 + seg * 16 + 8) = *(const u16x8*)(tmp + 8);
        }
    }
}

// ---------------- fused mid: heterogeneous grid, LDS-free -------------------
// Blocks 0..NT-1: 512 edges + logits/copy for 64 rows. Blocks NT..NT+NSC-1:
// 512 edges only (occupancy filler for the latency-bound atomic scatter).
// Atomics ISSUED first, results USED last — vmcnt wait hides behind the work.
__global__ __launch_bounds__(256) void k_mid(const void* __restrict__ x,
                                             const unsigned short* __restrict__ Batt,
                                             const int* __restrict__ ei,
                                             const int* __restrict__ flags,
                                             int* __restrict__ cnt,
                                             unsigned short* __restrict__ col_pad,
                                             unsigned short* __restrict__ x16,
                                             float* __restrict__ a_src,
                                             float* __restrict__ a_dst) {
    const int f64 = flags[0];
    const int base = blockIdx.x * EPB + threadIdx.x;
    int srcv[2], dstv[2], pos[2];
#pragma unroll
    for (int k = 0; k < 2; ++k) {
        int t = base + k * 256;
        if (t < N_EDGES) {
            if (f64) { srcv[k] = ei[2 * t]; dstv[k] = ei[2 * N_EDGES + 2 * t]; }
            else     { srcv[k] = ei[t];     dstv[k] = ei[N_EDGES + t]; }
        } else dstv[k] = -1;
    }
#pragma unroll
    for (int k = 0; k < 2; ++k)
        if (dstv[k] >= 0) pos[k] = atomicAdd(cnt + dstv[k], 1);
    if (blockIdx.x < NT) {                      // row block: logits + f16 copy
        if (flags[1]) row_body<float>((const float*)x, Batt, x16, a_src, a_dst);
        else          row_body<__hip_bfloat16>((const __hip_bfloat16*)x, Batt,
                                               x16, a_src, a_dst);
    }
    // ---- deferred scatter stores ----
#pragma unroll
    for (int k = 0; k < 2; ++k)
        if (dstv[k] >= 0 && pos[k] < CAP)
            col_pad[dstv[k] * CAP + pos[k]] = (unsigned short)srcv[k];
}

// 32 fma_mix per gathered 16B (8 f16 dims x 4 heads); acc layout [h*8+i]
__device__ __forceinline__ void fma32(u16x8 xv, float4 p, float* a) {
#pragma unroll
    for (int i = 0; i < 8; ++i) {
        float f = hbits(xv[i]);
        a[i]      = fmaf(p.x, f, a[i]);
        a[8 + i]  = fmaf(p.y, f, a[8 + i]);
        a[16 + i] = fmaf(p.z, f, a[16 + i]);
        a[24 + i] = fmaf(p.w, f, a[24 + i]);
    }
}

// ---------------- aggregate in INPUT space: s[h] = sum_j alpha_jh * x_j -----
// One wave per dst node. Edges = lanes 0..n-1, self loop = lane n, pads pe=0.
// Gather: 8 edges per b128 round — lane (g=lane>>3, d=lane&7) reads 16B slot d
// of edge g's 128B x16 row (4x less demand than xt rows; 6.4 MB footprint is
// mostly L2-resident). Per lane: 8 dims x 4 heads f32 accumulators; reduce
// over the 8 edge-groups with 3 shfl_xor steps; normalize by the wave-tree
// denominators; write s_cat[wid] f16 (lanes 0..31, 16B each, contiguous 512B).
__global__ __launch_bounds__(256) void k_aggregate(const int* __restrict__ cnt,
                                                   const unsigned short* __restrict__ col_pad,
                                                   const float* __restrict__ a_src,
                                                   const float* __restrict__ a_dst,
                                                   const unsigned short* __restrict__ x16,
                                                   unsigned short* __restrict__ s_cat) {
    __shared__ int    cS[4 * 64];
    __shared__ float4 peS[4 * 64];
    const int tid = threadIdx.x;
    const int wav = tid >> 6, lane = tid & 63;
    const int g = lane >> 3, d = lane & 7;
    const int wid = (blockIdx.x * blockDim.x + tid) >> 6;   // dst node
    if (wid >= N_NODES) return;
    int* cSw = cS + wav * 64;
    float4* peSw = peS + wav * 64;
    int n = cnt[wid]; n = n > (CAP - 1) ? (CAP - 1) : n;    // keep slot for self
    const float4 ad = ((const float4*)a_dst)[wid];          // uniform
    int mycol = wid;                                        // lane n = self loop
    if (lane < n) mycol = (int)col_pad[wid * CAP + lane];   // coalesced u16
    const float4 as = ((const float4*)a_src)[mycol];
    float e0 = as.x + ad.x, e1 = as.y + ad.y;
    float e2 = as.z + ad.z, e3 = as.w + ad.w;
    e0 = e0 > 0.f ? e0 : NEG_SLOPE * e0;  e1 = e1 > 0.f ? e1 : NEG_SLOPE * e1;
    e2 = e2 > 0.f ? e2 : NEG_SLOPE * e2;  e3 = e3 > 0.f ? e3 : NEG_SLOPE * e3;
    float4 pe = make_float4(exp2f(e0), exp2f(e1), exp2f(e2), exp2f(e3));
    if (lane > n) pe = make_float4(0.f, 0.f, 0.f, 0.f);     // pad lanes
    cSw[lane] = mycol << 7;                                 // x16 row BYTE offset
    peSw[lane] = pe;                                        // wave-sync LDS (in-order DS)
    // ---- gather & accumulate: 8 edges per round, x2 unrolled ---------------
    const char* xb = (const char*)x16 + d * 16;             // my 16B slice
    float acc[32];
#pragma unroll
    for (int k = 0; k < 32; ++k) acc[k] = 0.f;
    const int m8 = (n + 8) & ~7;                            // n+1 entries, pad to 8
    int j = 0;
    for (; j + 16 <= m8; j += 16) {
        int c0 = cSw[j + g], c1 = cSw[j + 8 + g];
        u16x8 x0 = *(const u16x8*)(xb + c0);
        u16x8 x1 = *(const u16x8*)(xb + c1);
        float4 p0 = peSw[j + g], p1 = peSw[j + 8 + g];
        fma32(x0, p0, acc);
        fma32(x1, p1, acc);
    }
    if (j < m8) {
        int c0 = cSw[j + g];
        u16x8 x0 = *(const u16x8*)(xb + c0);
        float4 p0 = peSw[j + g];
        fma32(x0, p0, acc);
    }
    // ---- reduce over the 8 edge-groups (lanes sharing d) -------------------
#pragma unroll
    for (int off = 8; off <= 32; off <<= 1)
#pragma unroll
        for (int k = 0; k < 32; ++k) acc[k] += __shfl_xor(acc[k], off, 64);
    // ---- denominators: one tree for the whole wave (pe=0 on pad lanes) -----
    float sp0 = pe.x, sp1 = pe.y, sp2 = pe.z, sp3 = pe.w;
#pragma unroll
    for (int off = 32; off > 0; off >>= 1) {
        sp0 += __shfl_xor(sp0, off, 64);
        sp1 += __shfl_xor(sp1, off, 64);
        sp2 += __shfl_xor(sp2, off, 64);
        sp3 += __shfl_xor(sp3, off, 64);
    }
    // ---- normalize + store s_cat[wid] (lanes 0..31, contiguous 512B) -------
    if (lane < 32) {
        const int h = lane >> 3;
        float rh = (h == 0) ? 1.f / sp0 : (h == 1) ? 1.f / sp1
                 : (h == 2) ? 1.f / sp2 : 1.f / sp3;
        u16x8 sv;
#define PK8(B) { sv[0]=f2h(acc[B+0]*rh); sv[1]=f2h(acc[B+1]*rh); \
                 sv[2]=f2h(acc[B+2]*rh); sv[3]=f2h(acc[B+3]*rh); \
                 sv[4]=f2h(acc[B+4]*rh); sv[5]=f2h(acc[B+5]*rh); \
                 sv[6]=f2h(acc[B+6]*rh); sv[7]=f2h(acc[B+7]*rh); }
        if      (h == 0) PK8(0)
        else if (h == 1) PK8(8)
        else if (h == 2) PK8(16)
        else             PK8(24)
#undef PK8
        *(u16x8*)((char*)s_cat + (size_t)wid * 512 + lane * 16) = sv;
    }
}

// ---------------- post: out = relu(s_cat @ Wstack/4 + bias) . fc_w + fc_b ----
// Streaming MFMA GEMM [N,256]@[256,64] (mean folded into Bpost), fused epilogue.
template <typename T>
__device__ __forceinline__ void post_body(const unsigned short* __restrict__ s_cat,
                                          const unsigned short* __restrict__ Bpost,
                                          const T* __restrict__ bias,
                                          const T* __restrict__ fc_w,
                                          const T* __restrict__ fc_b,
                                          float* __restrict__ out) {
    const int tid = threadIdx.x;
    const int wav = tid >> 6, lane = tid & 63;
    const int quad = lane >> 4, r15 = lane & 15;
    const int m0 = blockIdx.x * 64;
    int gr = m0 + wav * 16 + r15;
    if (gr >= N_NODES) gr = N_NODES - 1;        // clamp; stores guarded
    const half8* arow = (const half8*)((const char*)s_cat + (size_t)gr * 512);
    half8 af[8];
#pragma unroll
    for (int kt = 0; kt < 8; ++kt) af[kt] = arow[kt * 4 + quad];
    f32x4 acc[4];
#pragma unroll
    for (int nt = 0; nt < 4; ++nt) acc[nt] = (f32x4){0.f, 0.f, 0.f, 0.f};
    const half8* bp = (const half8*)Bpost;
#pragma unroll
    for (int kt = 0; kt < 8; ++kt)
#pragma unroll
        for (int nt = 0; nt < 4; ++nt)
            acc[nt] = __builtin_amdgcn_mfma_f32_16x16x32_f16(
                af[kt], bp[(kt * 4 + nt) * 64 + lane], acc[nt], 0, 0, 0);
    float bi[4], fw[4];
#pragma unroll
    for (int nt = 0; nt < 4; ++nt) {
        int c = nt * 16 + r15;
        bi[nt] = cvt<T>(bias[c]);
        fw[nt] = cvt<T>(fc_w[c]);
    }
    const float fcb = cvt<T>(fc_b[0]);
#pragma unroll
    for (int r = 0; r < 4; ++r) {
        float p = 0.f;
#pragma unroll
        for (int nt = 0; nt < 4; ++nt) {
            float o = acc[nt][r] + bi[nt];
            o = o > 0.f ? o : 0.f;              // relu
            p = fmaf(o, fw[nt], p);
        }
#pragma unroll
        for (int off = 8; off > 0; off >>= 1) p += __shfl_xor(p, off, 64);
        int row = m0 + wav * 16 + quad * 4 + r;
        if (r15 == 0 && row < N_NODES) out[row] = p + fcb;
    }
}

__global__ __launch_bounds__(256) void k_post(const unsigned short* __restrict__ s_cat,
                                              const unsigned short* __restrict__ Bpost,
                                              const void* __restrict__ bias,
                                              const void* __restrict__ fc_w,
                                              const void* __restrict__ fc_b,
                                              const int* __restrict__ flags,
                                              float* __restrict__ out) {
    if (flags[1])
        post_body<float>(s_cat, Bpost, (const float*)bias, (const float*)fc_w,
                         (const float*)fc_b, out);
    else
        post_body<__hip_bfloat16>(s_cat, Bpost, (const __hip_bfloat16*)bias,
                                  (const __hip_bfloat16*)fc_w,
                                  (const __hip_bfloat16*)fc_b, out);
}

extern "C" void kernel_launch(void* const* d_in, const int* in_sizes, int n_in,
                              void* d_out, int out_size, void* d_ws, size_t ws_size,
                              hipStream_t stream) {
    const void* x       = d_in[0];
    const int*  ei      = (const int*)d_in[1];
    const void* W       = d_in[2];
    const void* att_src = d_in[3];
    const void* att_dst = d_in[4];
    const void* bias    = d_in[5];
    const void* fc_w    = d_in[6];
    const void* fc_b    = d_in[7];
    float* out = (float*)d_out;

    char* wsb = (char*)d_ws;                                     // ~40.3 MB total
    unsigned short* x16   = (unsigned short*)wsb;                // 6.4 MB (f16 x)
    unsigned short* s_cat = (unsigned short*)(wsb + 6400000);    // 25.6 MB
    unsigned short* Batt  = (unsigned short*)(wsb + 32000000);   // 2 KB
    unsigned short* Bpost = (unsigned short*)(wsb + 32002048);   // 32 KB
    float* a_src = (float*)(wsb + 32034816);                     // 800 KB
    float* a_dst = (float*)(wsb + 32834816);                     // 800 KB
    unsigned short* col_pad = (unsigned short*)(wsb + 33634816); // 6.4 MB
    int* cnt   = (int*)(wsb + 40034816);                         // 200 KB
    int* flags = (int*)(wsb + 40234816);

    k_init<<<NB + 5, 256, 0, stream>>>((const unsigned*)x, ei, W, att_src,
                                       att_dst, cnt, flags, Batt, Bpost);
    k_mid<<<NT + NSC, 256, 0, stream>>>(x, Batt, ei, flags, cnt, col_pad,
                                        x16, a_src, a_dst);
    k_aggregate<<<((size_t)N_NODES * 64 + 255) / 256, 256, 0, stream>>>(
        cnt, col_pad, a_src, a_dst, x16, s_cat);
    k_post<<<NT, 256, 0, stream>>>(s_cat, Bpost, bias, fc_w, fc_b, flags, out);
}

// Round 3
// 179.237 us; speedup vs baseline: 1.1480x; 1.1480x over previous
//
#include <hip/hip_runtime.h>
#include <hip/hip_bf16.h>

#define N_NODES 50000
#define N_EDGES 800000
#define HEADS   4
#define NEG_SLOPE 0.2f
#define SB      256
#define NB      ((N_NODES + SB - 1) / SB)   // 196 blocks for cnt-zeroing
#define CAP     64                    // bucket capacity; P(deg>64)~1e-18/node
#define NT      ((N_NODES + 63) / 64)       // 782 row blocks
#define NSC     782                   // extra scatter-only blocks
#define EPB     512                   // edges per block (uniform split)
#define INV_LN2 1.44269504088896340736f

typedef __attribute__((ext_vector_type(8))) _Float16 half8;  // 8 f16 (4 VGPRs)
typedef __attribute__((ext_vector_type(4))) float f32x4;     // MFMA acc
typedef __attribute__((ext_vector_type(8))) unsigned short u16x8; // 16B of f16 bits

template <typename T> __device__ __forceinline__ float cvt(T v);
template <> __device__ __forceinline__ float cvt<float>(float v) { return v; }
template <> __device__ __forceinline__ float cvt<__hip_bfloat16>(__hip_bfloat16 v) {
    return __bfloat162float(v);
}
__device__ __forceinline__ unsigned short f2h(float f) {     // f32 -> f16 bits (RNE)
    _Float16 h = (_Float16)f;
    return __builtin_bit_cast(unsigned short, h);
}
__device__ __forceinline__ float hbits(unsigned short u) {   // f16 bits -> f32
    return (float)__builtin_bit_cast(_Float16, u);           // folds into v_fma_mix
}
__device__ __forceinline__ int probe_fp32(const unsigned* xw) {
    int sane = 0;
    for (int j = 0; j < 64; ++j) {
        unsigned e = (xw[j] >> 7) & 0xFF;    // exponent of low half viewed as bf16
        sane += (e >= 90 && e <= 141);
    }
    return sane < 32;                        // junk low halves => fp32 buffer
}
__device__ __forceinline__ float loadW(int isf32, const void* W, int idx) {
    return isf32 ? ((const float*)W)[idx]
                 : cvt<__hip_bfloat16>(((const __hip_bfloat16*)W)[idx]);
}

// load 8 contiguous elems as f16, vectorized (b128 loads)
template <typename T>
__device__ __forceinline__ void load8_f16(const T* p, _Float16* dst);
template <>
__device__ __forceinline__ void load8_f16<float>(const float* p, _Float16* dst) {
    float4 a = *(const float4*)p;            // 32B-aligned (offsets are 8-float mult.)
    float4 b = *(const float4*)(p + 4);
    dst[0] = (_Float16)a.x; dst[1] = (_Float16)a.y;
    dst[2] = (_Float16)a.z; dst[3] = (_Float16)a.w;
    dst[4] = (_Float16)b.x; dst[5] = (_Float16)b.y;
    dst[6] = (_Float16)b.z; dst[7] = (_Float16)b.w;
}
template <>
__device__ __forceinline__ void load8_f16<__hip_bfloat16>(const __hip_bfloat16* p,
                                                          _Float16* dst) {
    uint4 a = *(const uint4*)p;              // 8 bf16 = 16B
    const unsigned short* u = (const unsigned short*)&a;
#pragma unroll
    for (int j = 0; j < 8; ++j)
        dst[j] = (_Float16)__uint_as_float(((unsigned)u[j]) << 16);
}

// ------------- fused init: zero cnt + probes + pack Batt (att fold) + Bpost --
// flags[0]: edge_index is int64. flags[1]: float inputs are fp32.
// Blocks 0..NB-1: zero cnt (+ block 0 publishes probes).
// Block NB: att-fold Batt = (W @ a)/ln2 in MFMA-B layout (64K x 8N, K=64).
// Blocks NB+1..NB+4: Bpost = Wstack[256,64]/4 in MFMA-B layout (8 kt x 4 nt),
// where Wstack[h*64+k, c] = W[k, h*64+c]  (post-aggregation transform; the
// 1/HEADS mean is folded in). B layout (HW-verified): within one K=32 MFMA,
// value(l,j) = B[k=(l>>4)*8+j][n=l&15].
__global__ __launch_bounds__(256) void k_init(const unsigned* __restrict__ xw,
                                              const int* __restrict__ ei,
                                              const void* __restrict__ W,
                                              const void* __restrict__ att_src,
                                              const void* __restrict__ att_dst,
                                              int* __restrict__ cnt,
                                              int* __restrict__ flags,
                                              unsigned short* __restrict__ Batt,
                                              unsigned short* __restrict__ Bpost) {
    __shared__ float waS[256], waD[256];
    __shared__ int f32sh;
    if (blockIdx.x < NB) {
        int i = blockIdx.x * blockDim.x + threadIdx.x;
        if (i < N_NODES) cnt[i] = 0;
        if (blockIdx.x == 0 && threadIdx.x == 0) {
            int all0 = 1;
            for (int j = 1; j < 64; j += 2) all0 &= (ei[j] == 0);
            flags[0] = all0;
            flags[1] = probe_fp32(xw);
        }
        return;
    }
    const int pb = blockIdx.x - NB;          // 0 = att fold, 1..4 = Bpost
    if (threadIdx.x == 0) f32sh = probe_fp32(xw);   // local probe (race-free)
    __syncthreads();
    const int isf32 = f32sh;
    if (pb == 0) {
        int t = threadIdx.x, k = t >> 2, h = t & 3;
        float s = 0.f, d = 0.f;
        for (int c = 0; c < 64; ++c) {
            float w = loadW(isf32, W, k * 256 + h * 64 + c);
            float as = isf32 ? ((const float*)att_src)[h * 64 + c]
                             : cvt<__hip_bfloat16>(((const __hip_bfloat16*)att_src)[h * 64 + c]);
            float ad = isf32 ? ((const float*)att_dst)[h * 64 + c]
                             : cvt<__hip_bfloat16>(((const __hip_bfloat16*)att_dst)[h * 64 + c]);
            s = fmaf(w, as, s);
            d = fmaf(w, ad, d);
        }
        waS[t] = s * INV_LN2;
        waD[t] = d * INV_LN2;
        __syncthreads();
        if (threadIdx.x < 128) {
            int r = threadIdx.x;             // r = q*64 + l, q = K-half
            int q = (r >> 6) & 1, l = r & 63, n = l & 15;
            int kbase = q * 32 + ((l >> 4) & 3) * 8;
#pragma unroll
            for (int j = 0; j < 8; ++j) {
                int kk = kbase + j;
                float v = (n < 4) ? waS[kk * 4 + n]
                        : (n < 8) ? waD[kk * 4 + (n - 4)] : 0.f;
                Batt[r * 8 + j] = f2h(v);
            }
        }
    } else {
        // Bpost: tile t = kt*4+nt (t = 0..31); this block packs 8 tiles.
        const int sub = threadIdx.x >> 5, s = threadIdx.x & 31;
        const int t = (pb - 1) * 8 + sub;
        const int kt = t >> 2, nt = t & 3;
#pragma unroll
        for (int e = 0; e < 16; ++e) {
            int idx = s * 16 + e;            // 0..511 within tile
            int l = idx >> 3, j = idx & 7;
            int rs = kt * 32 + ((l >> 4) & 3) * 8 + j;   // row of Wstack (0..255)
            int h = rs >> 6, k_in = rs & 63;
            int c = nt * 16 + (l & 15);
            Bpost[t * 512 + l * 8 + j] =
                f2h(loadW(isf32, W, k_in * 256 + h * 64 + c) * 0.25f);
        }
    }
}

// ---------------- logits + x->f16 copy body (row blocks of k_mid) ------------
// Block = 64 rows, 4 waves; wave w: rows 16w..16w+15; single n-tile (Batt).
// C layout (HW-verified): col=lane&15, row=quad*4+reg. Cols 0..3 = a_src heads,
// 4..7 = a_dst heads (1/ln2-scaled) -> direct fp32 global writes.
template <typename T>
__device__ __forceinline__ void row_body(const T* __restrict__ x,
                                         const unsigned short* __restrict__ Batt,
                                         unsigned short* __restrict__ x16,
                                         float* __restrict__ a_src,
                                         float* __restrict__ a_dst) {
    const int tid = threadIdx.x;
    const int wav = tid >> 6, lane = tid & 63;
    const int quad = lane >> 4, r15 = lane & 15;
    const int m0 = blockIdx.x * 64;
    int gr = m0 + wav * 16 + r15;               // this lane's A row (m = lane&15)
    if (gr >= N_NODES) gr = N_NODES - 1;        // clamp; stores guarded
    half8 afrag[2];
#pragma unroll
    for (int q = 0; q < 2; ++q) {
        _Float16 tmp[8];
        load8_f16<T>(x + (size_t)gr * 64 + q * 32 + quad * 8, tmp);
#pragma unroll
        for (int j = 0; j < 8; ++j) afrag[q][j] = tmp[j];
    }
    f32x4 acc = (f32x4){0.f, 0.f, 0.f, 0.f};
    const half8* bp = (const half8*)Batt;
    acc = __builtin_amdgcn_mfma_f32_16x16x32_f16(afrag[0], bp[lane], acc, 0, 0, 0);
    acc = __builtin_amdgcn_mfma_f32_16x16x32_f16(afrag[1], bp[64 + lane], acc, 0, 0, 0);
    if (r15 < 8) {
#pragma unroll
        for (int r = 0; r < 4; ++r) {
            int grow = m0 + wav * 16 + quad * 4 + r;
            if (grow < N_NODES) {
                if (r15 < 4) a_src[grow * HEADS + r15]       = acc[r];
                else         a_dst[grow * HEADS + (r15 - 4)] = acc[r];
            }
        }
    }
    // ---- f16 copy of x (gather source for k_agg): row = tid>>2, 16 dims ----
    {
        int row = m0 + (tid >> 2), seg = tid & 3;
        if (row < N_NODES) {
            _Float16 tmp[16];
            load8_f16<T>(x + (size_t)row * 64 + seg * 16, tmp);
            load8_f16<T>(x + (size_t)row * 64 + seg * 16 + 8, tmp + 8);
            *(u16x8*)(x16 + (size_t)row * 64 + seg * 16)     = *(const u16x8*)tmp;
            *(u16x8*)(x16 + (size_t)row * 64 + seg * 16 + 8) = *(const u16x8*)(tmp + 8);
        }
    }
}

// ---------------- fused mid: heterogeneous grid, LDS-free -------------------
// Blocks 0..NT-1: 512 edges + logits/copy for 64 rows. Blocks NT..NT+NSC-1:
// 512 edges only (occupancy filler for the latency-bound atomic scatter).
// Atomics ISSUED first, results USED last — vmcnt wait hides behind the work.
__global__ __launch_bounds__(256) void k_mid(const void* __restrict__ x,
                                             const unsigned short* __restrict__ Batt,
                                             const int* __restrict__ ei,
                                             const int* __restrict__ flags,
                                             int* __restrict__ cnt,
                                             unsigned short* __restrict__ col_pad,
                                             unsigned short* __restrict__ x16,
                                             float* __restrict__ a_src,
                                             float* __restrict__ a_dst) {
    const int f64 = flags[0];
    const int base = blockIdx.x * EPB + threadIdx.x;
    int srcv[2], dstv[2], pos[2];
#pragma unroll
    for (int k = 0; k < 2; ++k) {
        int t = base + k * 256;
        if (t < N_EDGES) {
            if (f64) {                          // int64: full-line int2 loads
                int2 s2 = *(const int2*)(ei + 2 * t);
                int2 d2 = *(const int2*)(ei + 2 * N_EDGES + 2 * t);
                srcv[k] = s2.x; dstv[k] = d2.x;
            } else { srcv[k] = ei[t]; dstv[k] = ei[N_EDGES + t]; }
        } else dstv[k] = -1;
    }
#pragma unroll
    for (int k = 0; k < 2; ++k)
        if (dstv[k] >= 0) pos[k] = atomicAdd(cnt + dstv[k], 1);
    if (blockIdx.x < NT) {                      // row block: logits + f16 copy
        if (flags[1]) row_body<float>((const float*)x, Batt, x16, a_src, a_dst);
        else          row_body<__hip_bfloat16>((const __hip_bfloat16*)x, Batt,
                                               x16, a_src, a_dst);
    }
    // ---- deferred scatter stores ----
#pragma unroll
    for (int k = 0; k < 2; ++k)
        if (dstv[k] >= 0 && pos[k] < CAP)
            col_pad[dstv[k] * CAP + pos[k]] = (unsigned short)srcv[k];
}

// ---------------- aggregate in INPUT space: s[h] = sum_j alpha_jh * x_j -----
// One wave per dst node. Edges = lanes 0..n-1, self loop = lane n, pads pe=0.
// DS-minimal design (R2 post-mortem: 140 DS-ops/wave = 68us DS-pipe floor):
//   - lane l5 owns dims (2*l5, 2*l5+1); halves (hlf) split edges -> dword
//     gathers, 2 rows per instr, only 8 f32 accumulators per lane.
//   - col list stored PARITY-INTERLEAVED (edge e -> slot (e&1)*32+(e>>1)) so
//     one ds_read_b128 yields 4 rounds of columns for my half.
//   - tail: 8-acc fold (8 shfl) + denominator tree (24 shfl). ~45 DS/wave.
__global__ __launch_bounds__(256) void k_aggregate(const int* __restrict__ cnt,
                                                   const unsigned short* __restrict__ col_pad,
                                                   const float* __restrict__ a_src,
                                                   const float* __restrict__ a_dst,
                                                   const unsigned short* __restrict__ x16,
                                                   unsigned short* __restrict__ s_cat) {
    __shared__ __align__(16) int cS[4][64];     // [wav][slot], parity-interleaved
    __shared__ float4 peS[4][64];
    const int tid = threadIdx.x;
    const int wav = tid >> 6, lane = tid & 63;
    const int hlf = lane >> 5, l5 = lane & 31;
    const int wid = (blockIdx.x * blockDim.x + tid) >> 6;   // dst node
    if (wid >= N_NODES) return;
    int* cSw = cS[wav];
    float4* peSw = peS[wav];
    int n = cnt[wid]; n = n > (CAP - 1) ? (CAP - 1) : n;    // keep slot for self
    const float4 ad = ((const float4*)a_dst)[wid];          // uniform
    int mycol = wid;                                        // lane n = self loop
    if (lane < n) mycol = (int)col_pad[wid * CAP + lane];   // coalesced u16
    const float4 as = ((const float4*)a_src)[mycol];
    float e0 = as.x + ad.x, e1 = as.y + ad.y;
    float e2 = as.z + ad.z, e3 = as.w + ad.w;
    e0 = e0 > 0.f ? e0 : NEG_SLOPE * e0;  e1 = e1 > 0.f ? e1 : NEG_SLOPE * e1;
    e2 = e2 > 0.f ? e2 : NEG_SLOPE * e2;  e3 = e3 > 0.f ? e3 : NEG_SLOPE * e3;
    float4 pe = make_float4(exp2f(e0), exp2f(e1), exp2f(e2), exp2f(e3));
    if (lane > n) pe = make_float4(0.f, 0.f, 0.f, 0.f);     // pad lanes
    const int slot = (lane & 1) * 32 + (lane >> 1);         // parity interleave
    cSw[slot] = mycol << 7;                                 // x16 row BYTE offset
    peS[wav][slot] = pe;                                    // wave-sync LDS (in-order DS)
    // ---- gather loop: per round, half h processes edge 2r+h (dword/lane) ---
    const char* xb = (const char*)x16 + l5 * 4;             // my dim-pair slice
    float a0 = 0.f, a1 = 0.f, a2 = 0.f, a3 = 0.f;           // a[h*2+t]
    float a4 = 0.f, a5 = 0.f, a6 = 0.f, a7 = 0.f;
    const int nr = (n + 2) >> 1;                            // rounds (n+1 entries)
    const int*    cB = cSw + hlf * 32;                      // my half's col list
    const float4* pB = peSw + hlf * 32;
#define ACC2(D, P) { float x0 = hbits((unsigned short)((D) & 0xffff)); \
                     float x1 = hbits((unsigned short)((D) >> 16)); \
                     a0 = fmaf((P).x, x0, a0); a1 = fmaf((P).x, x1, a1); \
                     a2 = fmaf((P).y, x0, a2); a3 = fmaf((P).y, x1, a3); \
                     a4 = fmaf((P).z, x0, a4); a5 = fmaf((P).z, x1, a5); \
                     a6 = fmaf((P).w, x0, a6); a7 = fmaf((P).w, x1, a7); }
    int r = 0;
    for (; r + 4 <= nr; r += 4) {
        const int4 cc = *(const int4*)(cB + r);             // 4 rounds of cols
        unsigned dA = *(const unsigned*)(xb + cc.x);
        unsigned dB = *(const unsigned*)(xb + cc.y);
        unsigned dC = *(const unsigned*)(xb + cc.z);
        unsigned dD = *(const unsigned*)(xb + cc.w);
        float4 pA = pB[r], pBv = pB[r + 1], pC = pB[r + 2], pD = pB[r + 3];
        ACC2(dA, pA); ACC2(dB, pBv); ACC2(dC, pC); ACC2(dD, pD);
    }
    for (; r < nr; ++r) {
        int c = cB[r];
        unsigned d = *(const unsigned*)(xb + c);
        float4 p = pB[r];
        ACC2(d, p);
    }
#undef ACC2
    // ---- fold the two 32-lane halves (same dims, disjoint edges) -----------
    a0 += __shfl_xor(a0, 32, 64); a1 += __shfl_xor(a1, 32, 64);
    a2 += __shfl_xor(a2, 32, 64); a3 += __shfl_xor(a3, 32, 64);
    a4 += __shfl_xor(a4, 32, 64); a5 += __shfl_xor(a5, 32, 64);
    a6 += __shfl_xor(a6, 32, 64); a7 += __shfl_xor(a7, 32, 64);
    // ---- denominators: one tree for the whole wave (pe=0 on pad lanes) -----
    float sp0 = pe.x, sp1 = pe.y, sp2 = pe.z, sp3 = pe.w;
#pragma unroll
    for (int off = 32; off > 0; off >>= 1) {
        sp0 += __shfl_xor(sp0, off, 64);
        sp1 += __shfl_xor(sp1, off, 64);
        sp2 += __shfl_xor(sp2, off, 64);
        sp3 += __shfl_xor(sp3, off, 64);
    }
    const float r0 = 1.f / sp0, r1 = 1.f / sp1;
    const float r2 = 1.f / sp2, r3 = 1.f / sp3;
    // ---- normalize + store s_cat[wid][h*64 + 2*l5] (dword per head) --------
    unsigned short* sr = s_cat + (size_t)wid * 256 + 2 * l5;
    unsigned w0 = (unsigned)f2h(a0 * r0) | ((unsigned)f2h(a1 * r0) << 16);
    unsigned w1 = (unsigned)f2h(a2 * r1) | ((unsigned)f2h(a3 * r1) << 16);
    unsigned w2 = (unsigned)f2h(a4 * r2) | ((unsigned)f2h(a5 * r2) << 16);
    unsigned w3 = (unsigned)f2h(a6 * r3) | ((unsigned)f2h(a7 * r3) << 16);
    *(unsigned*)(sr)       = w0;
    *(unsigned*)(sr + 64)  = w1;
    *(unsigned*)(sr + 128) = w2;
    *(unsigned*)(sr + 192) = w3;
}

// ---------------- post: out = relu(s_cat @ Wstack/4 + bias) . fc_w + fc_b ----
// Streaming MFMA GEMM [N,256]@[256,64] (mean folded into Bpost), fused epilogue.
template <typename T>
__device__ __forceinline__ void post_body(const unsigned short* __restrict__ s_cat,
                                          const unsigned short* __restrict__ Bpost,
                                          const T* __restrict__ bias,
                                          const T* __restrict__ fc_w,
                                          const T* __restrict__ fc_b,
                                          float* __restrict__ out) {
    const int tid = threadIdx.x;
    const int wav = tid >> 6, lane = tid & 63;
    const int quad = lane >> 4, r15 = lane & 15;
    const int m0 = blockIdx.x * 64;
    int gr = m0 + wav * 16 + r15;
    if (gr >= N_NODES) gr = N_NODES - 1;        // clamp; stores guarded
    const half8* arow = (const half8*)((const char*)s_cat + (size_t)gr * 512);
    half8 af[8];
#pragma unroll
    for (int kt = 0; kt < 8; ++kt) af[kt] = arow[kt * 4 + quad];
    f32x4 acc[4];
#pragma unroll
    for (int nt = 0; nt < 4; ++nt) acc[nt] = (f32x4){0.f, 0.f, 0.f, 0.f};
    const half8* bp = (const half8*)Bpost;
#pragma unroll
    for (int kt = 0; kt < 8; ++kt)
#pragma unroll
        for (int nt = 0; nt < 4; ++nt)
            acc[nt] = __builtin_amdgcn_mfma_f32_16x16x32_f16(
                af[kt], bp[(kt * 4 + nt) * 64 + lane], acc[nt], 0, 0, 0);
    float bi[4], fw[4];
#pragma unroll
    for (int nt = 0; nt < 4; ++nt) {
        int c = nt * 16 + r15;
        bi[nt] = cvt<T>(bias[c]);
        fw[nt] = cvt<T>(fc_w[c]);
    }
    const float fcb = cvt<T>(fc_b[0]);
#pragma unroll
    for (int r = 0; r < 4; ++r) {
        float p = 0.f;
#pragma unroll
        for (int nt = 0; nt < 4; ++nt) {
            float o = acc[nt][r] + bi[nt];
            o = o > 0.f ? o : 0.f;              // relu
            p = fmaf(o, fw[nt], p);
        }
#pragma unroll
        for (int off = 8; off > 0; off >>= 1) p += __shfl_xor(p, off, 64);
        int row = m0 + wav * 16 + quad * 4 + r;
        if (r15 == 0 && row < N_NODES) out[row] = p + fcb;
    }
}

__global__ __launch_bounds__(256) void k_post(const unsigned short* __restrict__ s_cat,
                                              const unsigned short* __restrict__ Bpost,
                                              const void* __restrict__ bias,
                                              const void* __restrict__ fc_w,
                                              const void* __restrict__ fc_b,
                                              const int* __restrict__ flags,
                                              float* __restrict__ out) {
    if (flags[1])
        post_body<float>(s_cat, Bpost, (const float*)bias, (const float*)fc_w,
                         (const float*)fc_b, out);
    else
        post_body<__hip_bfloat16>(s_cat, Bpost, (const __hip_bfloat16*)bias,
                                  (const __hip_bfloat16*)fc_w,
                                  (const __hip_bfloat16*)fc_b, out);
}

extern "C" void kernel_launch(void* const* d_in, const int* in_sizes, int n_in,
                              void* d_out, int out_size, void* d_ws, size_t ws_size,
                              hipStream_t stream) {
    const void* x       = d_in[0];
    const int*  ei      = (const int*)d_in[1];
    const void* W       = d_in[2];
    const void* att_src = d_in[3];
    const void* att_dst = d_in[4];
    const void* bias    = d_in[5];
    const void* fc_w    = d_in[6];
    const void* fc_b    = d_in[7];
    float* out = (float*)d_out;

    char* wsb = (char*)d_ws;                                     // ~40.3 MB total
    unsigned short* x16   = (unsigned short*)wsb;                // 6.4 MB (f16 x)
    unsigned short* s_cat = (unsigned short*)(wsb + 6400000);    // 25.6 MB
    unsigned short* Batt  = (unsigned short*)(wsb + 32000000);   // 2 KB
    unsigned short* Bpost = (unsigned short*)(wsb + 32002048);   // 32 KB
    float* a_src = (float*)(wsb + 32034816);                     // 800 KB
    float* a_dst = (float*)(wsb + 32834816);                     // 800 KB
    unsigned short* col_pad = (unsigned short*)(wsb + 33634816); // 6.4 MB
    int* cnt   = (int*)(wsb + 40034816);                         // 200 KB
    int* flags = (int*)(wsb + 40234816);

    k_init<<<NB + 5, 256, 0, stream>>>((const unsigned*)x, ei, W, att_src,
                                       att_dst, cnt, flags, Batt, Bpost);
    k_mid<<<NT + NSC, 256, 0, stream>>>(x, Batt, ei, flags, cnt, col_pad,
                                        x16, a_src, a_dst);
    k_aggregate<<<((size_t)N_NODES * 64 + 255) / 256, 256, 0, stream>>>(
        cnt, col_pad, a_src, a_dst, x16, s_cat);
    k_post<<<NT, 256, 0, stream>>>(s_cat, Bpost, bias, fc_w, fc_b, flags, out);
}

// Round 4
// 174.423 us; speedup vs baseline: 1.1797x; 1.0276x over previous
//
#include <hip/hip_runtime.h>
#include <hip/hip_bf16.h>

#define N_NODES 50000
#define N_EDGES 800000
#define HEADS   4
#define NEG_SLOPE 0.2f
#define CAP     64                    // bucket capacity; P(deg>64)~1e-18/node
#define NT      ((N_NODES + 63) / 64)       // 782 row blocks
#define EPB     2048                  // edges per edge-block
#define NEB     ((N_EDGES + EPB - 1) / EPB) // 391 edge blocks (even blockIdx)
#define NREG    98                    // regions of 512 nodes (dst>>9)
#define QCAP    9216                  // queue cap/region: mean 8192 + 11 sigma
#define INV_LN2 1.44269504088896340736f

typedef __attribute__((ext_vector_type(8))) _Float16 half8;  // 8 f16 (4 VGPRs)
typedef __attribute__((ext_vector_type(4))) float f32x4;     // MFMA acc
typedef __attribute__((ext_vector_type(8))) unsigned short u16x8; // 16B of f16 bits

template <typename T> __device__ __forceinline__ float cvt(T v);
template <> __device__ __forceinline__ float cvt<float>(float v) { return v; }
template <> __device__ __forceinline__ float cvt<__hip_bfloat16>(__hip_bfloat16 v) {
    return __bfloat162float(v);
}
__device__ __forceinline__ unsigned short f2h(float f) {     // f32 -> f16 bits (RNE)
    _Float16 h = (_Float16)f;
    return __builtin_bit_cast(unsigned short, h);
}
__device__ __forceinline__ float hbits(unsigned short u) {   // f16 bits -> f32
    return (float)__builtin_bit_cast(_Float16, u);           // folds into v_fma_mix
}
__device__ __forceinline__ int probe_fp32(const unsigned* xw) {
    int sane = 0;
    for (int j = 0; j < 64; ++j) {
        unsigned e = (xw[j] >> 7) & 0xFF;    // exponent of low half viewed as bf16
        sane += (e >= 90 && e <= 141);
    }
    return sane < 32;                        // junk low halves => fp32 buffer
}
__device__ __forceinline__ float loadW(int isf32, const void* W, int idx) {
    return isf32 ? ((const float*)W)[idx]
                 : cvt<__hip_bfloat16>(((const __hip_bfloat16*)W)[idx]);
}

// load 8 contiguous elems as f16, vectorized (b128 loads)
template <typename T>
__device__ __forceinline__ void load8_f16(const T* p, _Float16* dst);
template <>
__device__ __forceinline__ void load8_f16<float>(const float* p, _Float16* dst) {
    float4 a = *(const float4*)p;            // 32B-aligned (offsets are 8-float mult.)
    float4 b = *(const float4*)(p + 4);
    dst[0] = (_Float16)a.x; dst[1] = (_Float16)a.y;
    dst[2] = (_Float16)a.z; dst[3] = (_Float16)a.w;
    dst[4] = (_Float16)b.x; dst[5] = (_Float16)b.y;
    dst[6] = (_Float16)b.z; dst[7] = (_Float16)b.w;
}
template <>
__device__ __forceinline__ void load8_f16<__hip_bfloat16>(const __hip_bfloat16* p,
                                                          _Float16* dst) {
    uint4 a = *(const uint4*)p;              // 8 bf16 = 16B
    const unsigned short* u = (const unsigned short*)&a;
#pragma unroll
    for (int j = 0; j < 8; ++j)
        dst[j] = (_Float16)__uint_as_float(((unsigned)u[j]) << 16);
}

// ------------- fused init: probes + zero qcnt + pack Batt + Bpost -----------
// flags[0]: edge_index is int64. flags[1]: float inputs are fp32.
// Block 0: flags + zero qcnt. Block 1: att-fold Batt = (W @ a)/ln2 in MFMA-B
// layout. Blocks 2..5: Bpost = Wstack[256,64]/4 in MFMA-B layout, where
// Wstack[h*64+k, c] = W[k, h*64+c] (mean folded). cnt zeroing GONE (k_scat
// writes cnt densely). B layout (HW-verified): value(l,j)=B[k=(l>>4)*8+j][n=l&15].
__global__ __launch_bounds__(256) void k_init(const unsigned* __restrict__ xw,
                                              const int* __restrict__ ei,
                                              const void* __restrict__ W,
                                              const void* __restrict__ att_src,
                                              const void* __restrict__ att_dst,
                                              int* __restrict__ qcnt,
                                              int* __restrict__ flags,
                                              unsigned short* __restrict__ Batt,
                                              unsigned short* __restrict__ Bpost) {
    __shared__ float waS[256], waD[256];
    __shared__ int f32sh;
    if (blockIdx.x == 0) {
        if (threadIdx.x < NREG) qcnt[threadIdx.x] = 0;
        if (threadIdx.x == 0) {
            int all0 = 1;
            for (int j = 1; j < 64; j += 2) all0 &= (ei[j] == 0);
            flags[0] = all0;
            flags[1] = probe_fp32(xw);
        }
        return;
    }
    const int pb = blockIdx.x - 1;           // 0 = att fold, 1..4 = Bpost
    if (threadIdx.x == 0) f32sh = probe_fp32(xw);   // local probe (race-free)
    __syncthreads();
    const int isf32 = f32sh;
    if (pb == 0) {
        int t = threadIdx.x, k = t >> 2, h = t & 3;
        float s = 0.f, d = 0.f;
        for (int c = 0; c < 64; ++c) {
            float w = loadW(isf32, W, k * 256 + h * 64 + c);
            float as = isf32 ? ((const float*)att_src)[h * 64 + c]
                             : cvt<__hip_bfloat16>(((const __hip_bfloat16*)att_src)[h * 64 + c]);
            float ad = isf32 ? ((const float*)att_dst)[h * 64 + c]
                             : cvt<__hip_bfloat16>(((const __hip_bfloat16*)att_dst)[h * 64 + c]);
            s = fmaf(w, as, s);
            d = fmaf(w, ad, d);
        }
        waS[t] = s * INV_LN2;
        waD[t] = d * INV_LN2;
        __syncthreads();
        if (threadIdx.x < 128) {
            int r = threadIdx.x;             // r = q*64 + l, q = K-half
            int q = (r >> 6) & 1, l = r & 63, n = l & 15;
            int kbase = q * 32 + ((l >> 4) & 3) * 8;
#pragma unroll
            for (int j = 0; j < 8; ++j) {
                int kk = kbase + j;
                float v = (n < 4) ? waS[kk * 4 + n]
                        : (n < 8) ? waD[kk * 4 + (n - 4)] : 0.f;
                Batt[r * 8 + j] = f2h(v);
            }
        }
    } else {
        // Bpost: tile t = kt*4+nt (t = 0..31); this block packs 8 tiles.
        const int sub = threadIdx.x >> 5, s = threadIdx.x & 31;
        const int t = (pb - 1) * 8 + sub;
        const int kt = t >> 2, nt = t & 3;
#pragma unroll
        for (int e = 0; e < 16; ++e) {
            int idx = s * 16 + e;            // 0..511 within tile
            int l = idx >> 3, j = idx & 7;
            int rs = kt * 32 + ((l >> 4) & 3) * 8 + j;   // row of Wstack (0..255)
            int h = rs >> 6, k_in = rs & 63;
            int c = nt * 16 + (l & 15);
            Bpost[t * 512 + l * 8 + j] =
                f2h(loadW(isf32, W, k_in * 256 + h * 64 + c) * 0.25f);
        }
    }
}

// ---------------- logits + x->f16 copy body (all k_mid blocks) ---------------
// Block = 64 rows, 4 waves; wave w: rows 16w..16w+15; single n-tile (Batt).
// C layout (HW-verified): col=lane&15, row=quad*4+reg. Cols 0..3 = a_src heads,
// 4..7 = a_dst heads (1/ln2-scaled) -> direct fp32 global writes. NO syncthreads.
template <typename T>
__device__ __forceinline__ void row_body(const T* __restrict__ x,
                                         const unsigned short* __restrict__ Batt,
                                         unsigned short* __restrict__ x16,
                                         float* __restrict__ a_src,
                                         float* __restrict__ a_dst) {
    const int tid = threadIdx.x;
    const int wav = tid >> 6, lane = tid & 63;
    const int quad = lane >> 4, r15 = lane & 15;
    const int m0 = blockIdx.x * 64;
    int gr = m0 + wav * 16 + r15;               // this lane's A row (m = lane&15)
    if (gr >= N_NODES) gr = N_NODES - 1;        // clamp; stores guarded
    half8 afrag[2];
#pragma unroll
    for (int q = 0; q < 2; ++q) {
        _Float16 tmp[8];
        load8_f16<T>(x + (size_t)gr * 64 + q * 32 + quad * 8, tmp);
#pragma unroll
        for (int j = 0; j < 8; ++j) afrag[q][j] = tmp[j];
    }
    f32x4 acc = (f32x4){0.f, 0.f, 0.f, 0.f};
    const half8* bp = (const half8*)Batt;
    acc = __builtin_amdgcn_mfma_f32_16x16x32_f16(afrag[0], bp[lane], acc, 0, 0, 0);
    acc = __builtin_amdgcn_mfma_f32_16x16x32_f16(afrag[1], bp[64 + lane], acc, 0, 0, 0);
    if (r15 < 8) {
#pragma unroll
        for (int r = 0; r < 4; ++r) {
            int grow = m0 + wav * 16 + quad * 4 + r;
            if (grow < N_NODES) {
                if (r15 < 4) a_src[grow * HEADS + r15]       = acc[r];
                else         a_dst[grow * HEADS + (r15 - 4)] = acc[r];
            }
        }
    }
    // ---- f16 copy of x (gather source for k_agg): row = tid>>2, 16 dims ----
    {
        int row = m0 + (tid >> 2), seg = tid & 3;
        if (row < N_NODES) {
            _Float16 tmp[16];
            load8_f16<T>(x + (size_t)row * 64 + seg * 16, tmp);
            load8_f16<T>(x + (size_t)row * 64 + seg * 16 + 8, tmp + 8);
            *(u16x8*)(x16 + (size_t)row * 64 + seg * 16)     = *(const u16x8*)tmp;
            *(u16x8*)(x16 + (size_t)row * 64 + seg * 16 + 8) = *(const u16x8*)(tmp + 8);
        }
    }
}

// ---------------- fused mid: rows + REGION-BUCKETED edge append -------------
// R3 post-mortem: direct u16 scatter into col_pad = 800K random 64B
// write-allocates = 51 MB HBM writes = the whole 48us. Replacement: even
// blocks bucket EPB=2048 edges into 98 region queues (region = dst>>9) as
// packed 4B records; per (block,region) chunk ~84B contiguous -> ~5 MB of
// mostly-full-line writes. Global atomics: 800K -> ~38K (one per
// block x region), issued before row_body so latency hides under it.
__global__ __launch_bounds__(256) void k_mid(const void* __restrict__ x,
                                             const unsigned short* __restrict__ Batt,
                                             const int* __restrict__ ei,
                                             const int* __restrict__ flags,
                                             int* __restrict__ qcnt,
                                             unsigned* __restrict__ queue,
                                             unsigned short* __restrict__ x16,
                                             float* __restrict__ a_src,
                                             float* __restrict__ a_dst) {
    __shared__ int hist[NREG];
    __shared__ int qbaseS[NREG];
    const int tid = threadIdx.x;
    const bool edge_blk = ((blockIdx.x & 1) == 0);   // interleaved for CU balance
    const int eb = blockIdx.x >> 1;                  // 0..390
    unsigned rec[8]; int reg[8], lpos[8];
    int histv = 0, mybase = 0;
    if (edge_blk) {
        if (tid < NREG) hist[tid] = 0;
        __syncthreads();
        const int f64 = flags[0];
        const int base = eb * EPB + tid;
#pragma unroll
        for (int k = 0; k < 8; ++k) {
            int t = base + k * 256;
            if (t < N_EDGES) {
                int s, d;
                if (f64) { s = ei[2 * t]; d = ei[2 * N_EDGES + 2 * t]; }
                else     { s = ei[t];     d = ei[N_EDGES + t]; }
                reg[k] = d >> 9;
                rec[k] = (unsigned)s | ((unsigned)d << 16);
            } else reg[k] = -1;
        }
#pragma unroll
        for (int k = 0; k < 8; ++k)
            if (reg[k] >= 0) lpos[k] = atomicAdd(&hist[reg[k]], 1);
        __syncthreads();
        if (tid < NREG) {
            histv = hist[tid];
            if (histv) mybase = atomicAdd(qcnt + tid, histv);  // issued pre-rows
        }
    }
    // ---- rows for ALL blocks (hides the qcnt atomic round trip) ----
    if (flags[1]) row_body<float>((const float*)x, Batt, x16, a_src, a_dst);
    else          row_body<__hip_bfloat16>((const __hip_bfloat16*)x, Batt,
                                           x16, a_src, a_dst);
    if (edge_blk) {
        if (tid < NREG) qbaseS[tid] = mybase;
        __syncthreads();
#pragma unroll
        for (int k = 0; k < 8; ++k)
            if (reg[k] >= 0) {
                int o = qbaseS[reg[k]] + lpos[k];
                if (o < QCAP)
                    queue[(size_t)reg[k] * QCAP + o] = rec[k];
            }
    }
}

// ---------------- scat: per-region queue -> col_pad + cnt (L2-local) --------
// One block per region (512 nodes, 64 KB col_pad window — single-XCD L2
// resident, flushes ~once). Positions via LDS atomics; cnt written densely.
__global__ __launch_bounds__(256) void k_scat(const unsigned* __restrict__ queue,
                                              const int* __restrict__ qcnt,
                                              unsigned short* __restrict__ col_pad,
                                              int* __restrict__ cnt) {
    __shared__ int cl[512];
    const int b = blockIdx.x, tid = threadIdx.x;
    const int base = b << 9;
    cl[tid] = 0; cl[tid + 256] = 0;
    __syncthreads();
    int m = qcnt[b]; m = m > QCAP ? QCAP : m;
    const unsigned* q = queue + (size_t)b * QCAP;
#pragma unroll 4
    for (int i = tid; i < m; i += 256) {
        unsigned rec = q[i];
        int d = rec >> 16, s = rec & 0xffff;
        int p = atomicAdd(&cl[d - base], 1);
        if (p < CAP) col_pad[(size_t)d * CAP + p] = (unsigned short)s;
    }
    __syncthreads();
    int j = base + tid;
    if (j < N_NODES) cnt[j] = cl[tid];
    j += 256;
    if (j < N_NODES) cnt[j] = cl[tid + 256];
}

// ---------------- aggregate in INPUT space: s[h] = sum_j alpha_jh * x_j -----
// One wave per dst node. Edges = lanes 0..n-1, self loop = lane n, pads pe=0.
// DS-minimal: lane l5 owns dims (2*l5,2*l5+1); halves split edges (dword
// gathers, 2 rows/instr); col list parity-interleaved so one ds_read_b128
// covers 4 rounds. Denominators accumulate IN-LOOP from the peS broadcasts
// already being read (R3 trim: replaces the 24-shuffle tree; tail = 12 shfl).
__global__ __launch_bounds__(256) void k_aggregate(const int* __restrict__ cnt,
                                                   const unsigned short* __restrict__ col_pad,
                                                   const float* __restrict__ a_src,
                                                   const float* __restrict__ a_dst,
                                                   const unsigned short* __restrict__ x16,
                                                   unsigned short* __restrict__ s_cat) {
    __shared__ __align__(16) int cS[4][64];     // [wav][slot], parity-interleaved
    __shared__ float4 peS[4][64];
    const int tid = threadIdx.x;
    const int wav = tid >> 6, lane = tid & 63;
    const int hlf = lane >> 5, l5 = lane & 31;
    const int wid = (blockIdx.x * blockDim.x + tid) >> 6;   // dst node
    if (wid >= N_NODES) return;
    int* cSw = cS[wav];
    float4* peSw = peS[wav];
    int n = cnt[wid]; n = n > (CAP - 1) ? (CAP - 1) : n;    // keep slot for self
    const float4 ad = ((const float4*)a_dst)[wid];          // uniform
    int mycol = wid;                                        // lane n = self loop
    if (lane < n) mycol = (int)col_pad[wid * CAP + lane];   // coalesced u16
    const float4 as = ((const float4*)a_src)[mycol];
    float e0 = as.x + ad.x, e1 = as.y + ad.y;
    float e2 = as.z + ad.z, e3 = as.w + ad.w;
    e0 = e0 > 0.f ? e0 : NEG_SLOPE * e0;  e1 = e1 > 0.f ? e1 : NEG_SLOPE * e1;
    e2 = e2 > 0.f ? e2 : NEG_SLOPE * e2;  e3 = e3 > 0.f ? e3 : NEG_SLOPE * e3;
    float4 pe = make_float4(exp2f(e0), exp2f(e1), exp2f(e2), exp2f(e3));
    if (lane > n) pe = make_float4(0.f, 0.f, 0.f, 0.f);     // pad lanes
    const int slot = (lane & 1) * 32 + (lane >> 1);         // parity interleave
    cSw[slot] = mycol << 7;                                 // x16 row BYTE offset
    peS[wav][slot] = pe;                                    // wave-sync LDS (in-order DS)
    // ---- gather loop: per round, half h processes edge 2r+h (dword/lane) ---
    const char* xb = (const char*)x16 + l5 * 4;             // my dim-pair slice
    float a0 = 0.f, a1 = 0.f, a2 = 0.f, a3 = 0.f;           // a[h*2+t]
    float a4 = 0.f, a5 = 0.f, a6 = 0.f, a7 = 0.f;
    float sp0 = 0.f, sp1 = 0.f, sp2 = 0.f, sp3 = 0.f;       // my half's denom
    const int nr = (n + 2) >> 1;                            // rounds (n+1 entries)
    const int*    cB = cSw + hlf * 32;                      // my half's col list
    const float4* pB = peSw + hlf * 32;
#define ACC2(D, P) { float x0 = hbits((unsigned short)((D) & 0xffff)); \
                     float x1 = hbits((unsigned short)((D) >> 16)); \
                     a0 = fmaf((P).x, x0, a0); a1 = fmaf((P).x, x1, a1); \
                     a2 = fmaf((P).y, x0, a2); a3 = fmaf((P).y, x1, a3); \
                     a4 = fmaf((P).z, x0, a4); a5 = fmaf((P).z, x1, a5); \
                     a6 = fmaf((P).w, x0, a6); a7 = fmaf((P).w, x1, a7); \
                     sp0 += (P).x; sp1 += (P).y; sp2 += (P).z; sp3 += (P).w; }
    int r = 0;
    for (; r + 4 <= nr; r += 4) {
        const int4 cc = *(const int4*)(cB + r);             // 4 rounds of cols
        unsigned dA = *(const unsigned*)(xb + cc.x);
        unsigned dB = *(const unsigned*)(xb + cc.y);
        unsigned dC = *(const unsigned*)(xb + cc.z);
        unsigned dD = *(const unsigned*)(xb + cc.w);
        float4 pA = pB[r], pBv = pB[r + 1], pC = pB[r + 2], pD = pB[r + 3];
        ACC2(dA, pA); ACC2(dB, pBv); ACC2(dC, pC); ACC2(dD, pD);
    }
    for (; r < nr; ++r) {
        int c = cB[r];
        unsigned d = *(const unsigned*)(xb + c);
        float4 p = pB[r];
        ACC2(d, p);
    }
#undef ACC2
    // ---- fold the two 32-lane halves (same dims, disjoint edges) -----------
    a0 += __shfl_xor(a0, 32, 64); a1 += __shfl_xor(a1, 32, 64);
    a2 += __shfl_xor(a2, 32, 64); a3 += __shfl_xor(a3, 32, 64);
    a4 += __shfl_xor(a4, 32, 64); a5 += __shfl_xor(a5, 32, 64);
    a6 += __shfl_xor(a6, 32, 64); a7 += __shfl_xor(a7, 32, 64);
    sp0 += __shfl_xor(sp0, 32, 64); sp1 += __shfl_xor(sp1, 32, 64);
    sp2 += __shfl_xor(sp2, 32, 64); sp3 += __shfl_xor(sp3, 32, 64);
    const float r0 = 1.f / sp0, r1 = 1.f / sp1;
    const float r2 = 1.f / sp2, r3 = 1.f / sp3;
    // ---- normalize + store s_cat[wid][h*64 + 2*l5] (dword per head) --------
    unsigned short* sr = s_cat + (size_t)wid * 256 + 2 * l5;
    unsigned w0 = (unsigned)f2h(a0 * r0) | ((unsigned)f2h(a1 * r0) << 16);
    unsigned w1 = (unsigned)f2h(a2 * r1) | ((unsigned)f2h(a3 * r1) << 16);
    unsigned w2 = (unsigned)f2h(a4 * r2) | ((unsigned)f2h(a5 * r2) << 16);
    unsigned w3 = (unsigned)f2h(a6 * r3) | ((unsigned)f2h(a7 * r3) << 16);
    *(unsigned*)(sr)       = w0;
    *(unsigned*)(sr + 64)  = w1;
    *(unsigned*)(sr + 128) = w2;
    *(unsigned*)(sr + 192) = w3;
}

// ---------------- post: out = relu(s_cat @ Wstack/4 + bias) . fc_w + fc_b ----
// Streaming MFMA GEMM [N,256]@[256,64] (mean folded into Bpost), fused epilogue.
template <typename T>
__device__ __forceinline__ void post_body(const unsigned short* __restrict__ s_cat,
                                          const unsigned short* __restrict__ Bpost,
                                          const T* __restrict__ bias,
                                          const T* __restrict__ fc_w,
                                          const T* __restrict__ fc_b,
                                          float* __restrict__ out) {
    const int tid = threadIdx.x;
    const int wav = tid >> 6, lane = tid & 63;
    const int quad = lane >> 4, r15 = lane & 15;
    const int m0 = blockIdx.x * 64;
    int gr = m0 + wav * 16 + r15;
    if (gr >= N_NODES) gr = N_NODES - 1;        // clamp; stores guarded
    const half8* arow = (const half8*)((const char*)s_cat + (size_t)gr * 512);
    half8 af[8];
#pragma unroll
    for (int kt = 0; kt < 8; ++kt) af[kt] = arow[kt * 4 + quad];
    f32x4 acc[4];
#pragma unroll
    for (int nt = 0; nt < 4; ++nt) acc[nt] = (f32x4){0.f, 0.f, 0.f, 0.f};
    const half8* bp = (const half8*)Bpost;
#pragma unroll
    for (int kt = 0; kt < 8; ++kt)
#pragma unroll
        for (int nt = 0; nt < 4; ++nt)
            acc[nt] = __builtin_amdgcn_mfma_f32_16x16x32_f16(
                af[kt], bp[(kt * 4 + nt) * 64 + lane], acc[nt], 0, 0, 0);
    float bi[4], fw[4];
#pragma unroll
    for (int nt = 0; nt < 4; ++nt) {
        int c = nt * 16 + r15;
        bi[nt] = cvt<T>(bias[c]);
        fw[nt] = cvt<T>(fc_w[c]);
    }
    const float fcb = cvt<T>(fc_b[0]);
#pragma unroll
    for (int r = 0; r < 4; ++r) {
        float p = 0.f;
#pragma unroll
        for (int nt = 0; nt < 4; ++nt) {
            float o = acc[nt][r] + bi[nt];
            o = o > 0.f ? o : 0.f;              // relu
            p = fmaf(o, fw[nt], p);
        }
#pragma unroll
        for (int off = 8; off > 0; off >>= 1) p += __shfl_xor(p, off, 64);
        int row = m0 + wav * 16 + quad * 4 + r;
        if (r15 == 0 && row < N_NODES) out[row] = p + fcb;
    }
}

__global__ __launch_bounds__(256) void k_post(const unsigned short* __restrict__ s_cat,
                                              const unsigned short* __restrict__ Bpost,
                                              const void* __restrict__ bias,
                                              const void* __restrict__ fc_w,
                                              const void* __restrict__ fc_b,
                                              const int* __restrict__ flags,
                                              float* __restrict__ out) {
    if (flags[1])
        post_body<float>(s_cat, Bpost, (const float*)bias, (const float*)fc_w,
                         (const float*)fc_b, out);
    else
        post_body<__hip_bfloat16>(s_cat, Bpost, (const __hip_bfloat16*)bias,
                                  (const __hip_bfloat16*)fc_w,
                                  (const __hip_bfloat16*)fc_b, out);
}

extern "C" void kernel_launch(void* const* d_in, const int* in_sizes, int n_in,
                              void* d_out, int out_size, void* d_ws, size_t ws_size,
                              hipStream_t stream) {
    const void* x       = d_in[0];
    const int*  ei      = (const int*)d_in[1];
    const void* W       = d_in[2];
    const void* att_src = d_in[3];
    const void* att_dst = d_in[4];
    const void* bias    = d_in[5];
    const void* fc_w    = d_in[6];
    const void* fc_b    = d_in[7];
    float* out = (float*)d_out;

    char* wsb = (char*)d_ws;                                     // ~40.3 MB total
    unsigned short* x16   = (unsigned short*)wsb;                // 6.4 MB (f16 x)
    unsigned short* s_cat = (unsigned short*)(wsb + 6400000);    // 25.6 MB
    unsigned* queue = (unsigned*)s_cat;          // 3.62 MB, ALIASES s_cat:
                                                 // k_scat reads it before k_agg writes
    unsigned short* Batt  = (unsigned short*)(wsb + 32000000);   // 2 KB
    unsigned short* Bpost = (unsigned short*)(wsb + 32002048);   // 32 KB
    float* a_src = (float*)(wsb + 32034816);                     // 800 KB
    float* a_dst = (float*)(wsb + 32834816);                     // 800 KB
    unsigned short* col_pad = (unsigned short*)(wsb + 33634816); // 6.4 MB
    int* cnt   = (int*)(wsb + 40034816);                         // 200 KB
    int* flags = (int*)(wsb + 40234816);                         // 8 B
    int* qcnt  = (int*)(wsb + 40234824);                         // 392 B

    k_init<<<6, 256, 0, stream>>>((const unsigned*)x, ei, W, att_src,
                                  att_dst, qcnt, flags, Batt, Bpost);
    k_mid<<<NT, 256, 0, stream>>>(x, Batt, ei, flags, qcnt, queue,
                                  x16, a_src, a_dst);
    k_scat<<<NREG, 256, 0, stream>>>(queue, qcnt, col_pad, cnt);
    k_aggregate<<<((size_t)N_NODES * 64 + 255) / 256, 256, 0, stream>>>(
        cnt, col_pad, a_src, a_dst, x16, s_cat);
    k_post<<<NT, 256, 0, stream>>>(s_cat, Bpost, bias, fc_w, fc_b, flags, out);
}

// Round 5
// 165.928 us; speedup vs baseline: 1.2401x; 1.0512x over previous
//
#include <hip/hip_runtime.h>
#include <hip/hip_bf16.h>

#define N_NODES 50000
#define N_EDGES 800000
#define HEADS   4
#define NEG_SLOPE 0.2f
#define CAP     64                    // bucket row: 63 edge slots + count in slot 63
#define NT      ((N_NODES + 63) / 64)       // 782 row blocks
#define EPB     2048                  // edges per edge-block
#define NREG    196                   // regions of 256 nodes (dst>>8)
#define QCAP    4608                  // queue cap/region: mean 4096 + 8 sigma
#define INV_LN2 1.44269504088896340736f

typedef __attribute__((ext_vector_type(8))) _Float16 half8;  // 8 f16 (4 VGPRs)
typedef __attribute__((ext_vector_type(4))) float f32x4;     // MFMA acc
typedef __attribute__((ext_vector_type(8))) unsigned short u16x8; // 16B of f16 bits

template <typename T> __device__ __forceinline__ float cvt(T v);
template <> __device__ __forceinline__ float cvt<float>(float v) { return v; }
template <> __device__ __forceinline__ float cvt<__hip_bfloat16>(__hip_bfloat16 v) {
    return __bfloat162float(v);
}
__device__ __forceinline__ unsigned short f2h(float f) {     // f32 -> f16 bits (RNE)
    _Float16 h = (_Float16)f;
    return __builtin_bit_cast(unsigned short, h);
}
__device__ __forceinline__ float hbits(unsigned short u) {   // f16 bits -> f32
    return (float)__builtin_bit_cast(_Float16, u);           // folds into v_fma_mix
}
__device__ __forceinline__ int probe_fp32(const unsigned* xw) {
    int sane = 0;
    for (int j = 0; j < 64; ++j) {
        unsigned e = (xw[j] >> 7) & 0xFF;    // exponent of low half viewed as bf16
        sane += (e >= 90 && e <= 141);
    }
    return sane < 32;                        // junk low halves => fp32 buffer
}
__device__ __forceinline__ float loadW(int isf32, const void* W, int idx) {
    return isf32 ? ((const float*)W)[idx]
                 : cvt<__hip_bfloat16>(((const __hip_bfloat16*)W)[idx]);
}

// load 8 contiguous elems as f16, vectorized (b128 loads)
template <typename T>
__device__ __forceinline__ void load8_f16(const T* p, _Float16* dst);
template <>
__device__ __forceinline__ void load8_f16<float>(const float* p, _Float16* dst) {
    float4 a = *(const float4*)p;            // 32B-aligned (offsets are 8-float mult.)
    float4 b = *(const float4*)(p + 4);
    dst[0] = (_Float16)a.x; dst[1] = (_Float16)a.y;
    dst[2] = (_Float16)a.z; dst[3] = (_Float16)a.w;
    dst[4] = (_Float16)b.x; dst[5] = (_Float16)b.y;
    dst[6] = (_Float16)b.z; dst[7] = (_Float16)b.w;
}
template <>
__device__ __forceinline__ void load8_f16<__hip_bfloat16>(const __hip_bfloat16* p,
                                                          _Float16* dst) {
    uint4 a = *(const uint4*)p;              // 8 bf16 = 16B
    const unsigned short* u = (const unsigned short*)&a;
#pragma unroll
    for (int j = 0; j < 8; ++j)
        dst[j] = (_Float16)__uint_as_float(((unsigned)u[j]) << 16);
}

// ------------- fused init: probes + zero qcnt + pack Batt + Bpost -----------
// flags[0]: edge_index is int64. flags[1]: float inputs are fp32.
// Block 0: flags + zero qcnt. Block 1: att-fold Batt = (W @ a)/ln2 in MFMA-B
// layout. Blocks 2..5: Bpost = Wstack[256,64]/4 in MFMA-B layout, where
// Wstack[h*64+k, c] = W[k, h*64+c] (mean folded). No cnt array at all (count
// lives in col_pad slot 63). B layout: value(l,j)=B[k=(l>>4)*8+j][n=l&15].
__global__ __launch_bounds__(256) void k_init(const unsigned* __restrict__ xw,
                                              const int* __restrict__ ei,
                                              const void* __restrict__ W,
                                              const void* __restrict__ att_src,
                                              const void* __restrict__ att_dst,
                                              int* __restrict__ qcnt,
                                              int* __restrict__ flags,
                                              unsigned short* __restrict__ Batt,
                                              unsigned short* __restrict__ Bpost) {
    __shared__ float waS[256], waD[256];
    __shared__ int f32sh;
    if (blockIdx.x == 0) {
        if (threadIdx.x < NREG) qcnt[threadIdx.x] = 0;
        if (threadIdx.x == 0) {
            int all0 = 1;
            for (int j = 1; j < 64; j += 2) all0 &= (ei[j] == 0);
            flags[0] = all0;
            flags[1] = probe_fp32(xw);
        }
        return;
    }
    const int pb = blockIdx.x - 1;           // 0 = att fold, 1..4 = Bpost
    if (threadIdx.x == 0) f32sh = probe_fp32(xw);   // local probe (race-free)
    __syncthreads();
    const int isf32 = f32sh;
    if (pb == 0) {
        int t = threadIdx.x, k = t >> 2, h = t & 3;
        float s = 0.f, d = 0.f;
        for (int c = 0; c < 64; ++c) {
            float w = loadW(isf32, W, k * 256 + h * 64 + c);
            float as = isf32 ? ((const float*)att_src)[h * 64 + c]
                             : cvt<__hip_bfloat16>(((const __hip_bfloat16*)att_src)[h * 64 + c]);
            float ad = isf32 ? ((const float*)att_dst)[h * 64 + c]
                             : cvt<__hip_bfloat16>(((const __hip_bfloat16*)att_dst)[h * 64 + c]);
            s = fmaf(w, as, s);
            d = fmaf(w, ad, d);
        }
        waS[t] = s * INV_LN2;
        waD[t] = d * INV_LN2;
        __syncthreads();
        if (threadIdx.x < 128) {
            int r = threadIdx.x;             // r = q*64 + l, q = K-half
            int q = (r >> 6) & 1, l = r & 63, n = l & 15;
            int kbase = q * 32 + ((l >> 4) & 3) * 8;
#pragma unroll
            for (int j = 0; j < 8; ++j) {
                int kk = kbase + j;
                float v = (n < 4) ? waS[kk * 4 + n]
                        : (n < 8) ? waD[kk * 4 + (n - 4)] : 0.f;
                Batt[r * 8 + j] = f2h(v);
            }
        }
    } else {
        // Bpost: tile t = kt*4+nt (t = 0..31); this block packs 8 tiles.
        const int sub = threadIdx.x >> 5, s = threadIdx.x & 31;
        const int t = (pb - 1) * 8 + sub;
        const int kt = t >> 2, nt = t & 3;
#pragma unroll
        for (int e = 0; e < 16; ++e) {
            int idx = s * 16 + e;            // 0..511 within tile
            int l = idx >> 3, j = idx & 7;
            int rs = kt * 32 + ((l >> 4) & 3) * 8 + j;   // row of Wstack (0..255)
            int h = rs >> 6, k_in = rs & 63;
            int c = nt * 16 + (l & 15);
            Bpost[t * 512 + l * 8 + j] =
                f2h(loadW(isf32, W, k_in * 256 + h * 64 + c) * 0.25f);
        }
    }
}

// ---------------- logits + x->f16 copy body (all k_mid blocks) ---------------
// Block = 64 rows, 4 waves; wave w: rows 16w..16w+15; single n-tile (Batt).
// C layout (HW-verified): col=lane&15, row=quad*4+reg. Cols 0..3 = a_src heads,
// 4..7 = a_dst heads (1/ln2-scaled) -> direct fp32 global writes. NO syncthreads.
template <typename T>
__device__ __forceinline__ void row_body(const T* __restrict__ x,
                                         const unsigned short* __restrict__ Batt,
                                         unsigned short* __restrict__ x16,
                                         float* __restrict__ a_src,
                                         float* __restrict__ a_dst) {
    const int tid = threadIdx.x;
    const int wav = tid >> 6, lane = tid & 63;
    const int quad = lane >> 4, r15 = lane & 15;
    const int m0 = blockIdx.x * 64;
    int gr = m0 + wav * 16 + r15;               // this lane's A row (m = lane&15)
    if (gr >= N_NODES) gr = N_NODES - 1;        // clamp; stores guarded
    half8 afrag[2];
#pragma unroll
    for (int q = 0; q < 2; ++q) {
        _Float16 tmp[8];
        load8_f16<T>(x + (size_t)gr * 64 + q * 32 + quad * 8, tmp);
#pragma unroll
        for (int j = 0; j < 8; ++j) afrag[q][j] = tmp[j];
    }
    f32x4 acc = (f32x4){0.f, 0.f, 0.f, 0.f};
    const half8* bp = (const half8*)Batt;
    acc = __builtin_amdgcn_mfma_f32_16x16x32_f16(afrag[0], bp[lane], acc, 0, 0, 0);
    acc = __builtin_amdgcn_mfma_f32_16x16x32_f16(afrag[1], bp[64 + lane], acc, 0, 0, 0);
    if (r15 < 8) {
#pragma unroll
        for (int r = 0; r < 4; ++r) {
            int grow = m0 + wav * 16 + quad * 4 + r;
            if (grow < N_NODES) {
                if (r15 < 4) a_src[grow * HEADS + r15]       = acc[r];
                else         a_dst[grow * HEADS + (r15 - 4)] = acc[r];
            }
        }
    }
    // ---- f16 copy of x (gather source for k_agg): row = tid>>2, 16 dims ----
    {
        int row = m0 + (tid >> 2), seg = tid & 3;
        if (row < N_NODES) {
            _Float16 tmp[16];
            load8_f16<T>(x + (size_t)row * 64 + seg * 16, tmp);
            load8_f16<T>(x + (size_t)row * 64 + seg * 16 + 8, tmp + 8);
            *(u16x8*)(x16 + (size_t)row * 64 + seg * 16)     = *(const u16x8*)tmp;
            *(u16x8*)(x16 + (size_t)row * 64 + seg * 16 + 8) = *(const u16x8*)(tmp + 8);
        }
    }
}

// ---------------- fused mid: rows + REGION-BUCKETED edge append -------------
// Even blocks bucket EPB=2048 edges into 196 region queues (region = dst>>8)
// as packed 4B records. Edge loads are PAIRED (int4/int2) for full-line use.
// Global atomics ~77K (one per block x region), issued before row_body so the
// round trip hides under it.
__global__ __launch_bounds__(256) void k_mid(const void* __restrict__ x,
                                             const unsigned short* __restrict__ Batt,
                                             const int* __restrict__ ei,
                                             const int* __restrict__ flags,
                                             int* __restrict__ qcnt,
                                             unsigned* __restrict__ queue,
                                             unsigned short* __restrict__ x16,
                                             float* __restrict__ a_src,
                                             float* __restrict__ a_dst) {
    __shared__ int hist[NREG];
    __shared__ int qbaseS[NREG];
    const int tid = threadIdx.x;
    const bool edge_blk = ((blockIdx.x & 1) == 0);   // interleaved for CU balance
    const int eb = blockIdx.x >> 1;                  // 0..390
    unsigned rec[8]; int reg[8], lpos[8];
    int histv = 0, mybase = 0;
    if (edge_blk) {
        if (tid < NREG) hist[tid] = 0;
        __syncthreads();
        const int f64 = flags[0];
        const int pbase = eb * 1024 + tid;           // pair index (2 edges/pair)
#pragma unroll
        for (int k = 0; k < 4; ++k) {
            int pid = pbase + k * 256;
            int e = 2 * pid;
            if (e < N_EDGES) {                       // N_EDGES even => e+1 valid
                int s0, d0, s1, d1;
                if (f64) {                           // 16B = 2 int64 edges
                    int4 sv = *(const int4*)(ei + 2 * e);
                    int4 dv = *(const int4*)(ei + 2 * N_EDGES + 2 * e);
                    s0 = sv.x; s1 = sv.z; d0 = dv.x; d1 = dv.z;
                } else {                             // 8B = 2 int32 edges
                    int2 sv = *(const int2*)(ei + e);
                    int2 dv = *(const int2*)(ei + N_EDGES + e);
                    s0 = sv.x; s1 = sv.y; d0 = dv.x; d1 = dv.y;
                }
                reg[2 * k]     = d0 >> 8;
                rec[2 * k]     = (unsigned)s0 | ((unsigned)d0 << 16);
                reg[2 * k + 1] = d1 >> 8;
                rec[2 * k + 1] = (unsigned)s1 | ((unsigned)d1 << 16);
            } else { reg[2 * k] = -1; reg[2 * k + 1] = -1; }
        }
#pragma unroll
        for (int k = 0; k < 8; ++k)
            if (reg[k] >= 0) lpos[k] = atomicAdd(&hist[reg[k]], 1);
        __syncthreads();
        if (tid < NREG) {
            histv = hist[tid];
            if (histv) mybase = atomicAdd(qcnt + tid, histv);  // issued pre-rows
        }
    }
    // ---- rows for ALL blocks (hides the qcnt atomic round trip) ----
    if (flags[1]) row_body<float>((const float*)x, Batt, x16, a_src, a_dst);
    else          row_body<__hip_bfloat16>((const __hip_bfloat16*)x, Batt,
                                           x16, a_src, a_dst);
    if (edge_blk) {
        if (tid < NREG) qbaseS[tid] = mybase;
        __syncthreads();
#pragma unroll
        for (int k = 0; k < 8; ++k)
            if (reg[k] >= 0) {
                int o = qbaseS[reg[k]] + lpos[k];
                if (o < QCAP)
                    queue[(size_t)reg[k] * QCAP + o] = rec[k];
            }
    }
}

// ---------------- scat: per-region queue -> col_pad (L2-local) --------------
// One block per 256-node region (32 KB col_pad window, single-XCD L2).
// Positions via LDS atomics. The per-node count is stored IN col_pad slot 63
// (valid: self-loop occupies lane n <= 63, so slot 63 is never an edge slot)
// -> k_aggregate needs ONE coalesced row read instead of cnt-load + row-load.
__global__ __launch_bounds__(256) void k_scat(const unsigned* __restrict__ queue,
                                              const int* __restrict__ qcnt,
                                              unsigned short* __restrict__ col_pad) {
    __shared__ int cl[256];
    const int b = blockIdx.x, tid = threadIdx.x;
    const int base = b << 8;
    cl[tid] = 0;
    __syncthreads();
    int m = qcnt[b]; m = m > QCAP ? QCAP : m;
    const unsigned* q = queue + (size_t)b * QCAP;
    for (int i = tid; i < m; i += 256) {
        unsigned rec = q[i];
        int d = rec >> 16, s = rec & 0xffff;
        int p = atomicAdd(&cl[d - base], 1);
        if (p < CAP - 1) col_pad[(size_t)d * CAP + p] = (unsigned short)s;
    }
    __syncthreads();
    int j = base + tid;
    if (j < N_NODES) {
        int c = cl[tid]; c = c > CAP - 1 ? CAP - 1 : c;
        col_pad[(size_t)j * CAP + (CAP - 1)] = (unsigned short)c;
    }
}

// ---------------- aggregate in INPUT space: s[h] = sum_j alpha_jh * x_j -----
// One wave per dst node. Edges = lanes 0..n-1, self loop = lane n, pads pe=0.
// n comes from the SAME coalesced col_pad row read (slot 63) via shfl —
// removes a dependent 400-cycle global load from the prologue. DS-minimal
// gather loop: lane l5 owns dims (2*l5,2*l5+1); halves split edges; col list
// parity-interleaved so one ds_read_b128 covers 4 rounds; denominators
// accumulate in-loop from the peS broadcasts already read.
__global__ __launch_bounds__(256) void k_aggregate(const unsigned short* __restrict__ col_pad,
                                                   const float* __restrict__ a_src,
                                                   const float* __restrict__ a_dst,
                                                   const unsigned short* __restrict__ x16,
                                                   unsigned short* __restrict__ s_cat) {
    __shared__ __align__(16) int cS[4][64];     // [wav][slot], parity-interleaved
    __shared__ float4 peS[4][64];
    const int tid = threadIdx.x;
    const int wav = tid >> 6, lane = tid & 63;
    const int hlf = lane >> 5, l5 = lane & 31;
    const int wid = (blockIdx.x * blockDim.x + tid) >> 6;   // dst node
    if (wid >= N_NODES) return;
    int* cSw = cS[wav];
    float4* peSw = peS[wav];
    const int cval = (int)col_pad[(size_t)wid * CAP + lane];  // one b128-coalesced read
    const int n = __shfl(cval, 63, 64);                     // count from slot 63
    const float4 ad = ((const float4*)a_dst)[wid];          // uniform
    const int mycol = (lane < n) ? cval : wid;              // lane n = self loop
    const float4 as = ((const float4*)a_src)[mycol];
    float e0 = as.x + ad.x, e1 = as.y + ad.y;
    float e2 = as.z + ad.z, e3 = as.w + ad.w;
    e0 = e0 > 0.f ? e0 : NEG_SLOPE * e0;  e1 = e1 > 0.f ? e1 : NEG_SLOPE * e1;
    e2 = e2 > 0.f ? e2 : NEG_SLOPE * e2;  e3 = e3 > 0.f ? e3 : NEG_SLOPE * e3;
    float4 pe = make_float4(exp2f(e0), exp2f(e1), exp2f(e2), exp2f(e3));
    if (lane > n) pe = make_float4(0.f, 0.f, 0.f, 0.f);     // pad lanes
    const int slot = (lane & 1) * 32 + (lane >> 1);         // parity interleave
    cSw[slot] = mycol << 7;                                 // x16 row BYTE offset
    peS[wav][slot] = pe;                                    // wave-sync LDS (in-order DS)
    // ---- gather loop: per round, half h processes edge 2r+h (dword/lane) ---
    const char* xb = (const char*)x16 + l5 * 4;             // my dim-pair slice
    float a0 = 0.f, a1 = 0.f, a2 = 0.f, a3 = 0.f;           // a[h*2+t]
    float a4 = 0.f, a5 = 0.f, a6 = 0.f, a7 = 0.f;
    float sp0 = 0.f, sp1 = 0.f, sp2 = 0.f, sp3 = 0.f;       // my half's denom
    const int nr = (n + 2) >> 1;                            // rounds (n+1 entries)
    const int*    cB = cSw + hlf * 32;                      // my half's col list
    const float4* pB = peSw + hlf * 32;
#define ACC2(D, P) { float x0 = hbits((unsigned short)((D) & 0xffff)); \
                     float x1 = hbits((unsigned short)((D) >> 16)); \
                     a0 = fmaf((P).x, x0, a0); a1 = fmaf((P).x, x1, a1); \
                     a2 = fmaf((P).y, x0, a2); a3 = fmaf((P).y, x1, a3); \
                     a4 = fmaf((P).z, x0, a4); a5 = fmaf((P).z, x1, a5); \
                     a6 = fmaf((P).w, x0, a6); a7 = fmaf((P).w, x1, a7); \
                     sp0 += (P).x; sp1 += (P).y; sp2 += (P).z; sp3 += (P).w; }
    int r = 0;
    for (; r + 4 <= nr; r += 4) {
        const int4 cc = *(const int4*)(cB + r);             // 4 rounds of cols
        unsigned dA = *(const unsigned*)(xb + cc.x);
        unsigned dB = *(const unsigned*)(xb + cc.y);
        unsigned dC = *(const unsigned*)(xb + cc.z);
        unsigned dD = *(const unsigned*)(xb + cc.w);
        float4 pA = pB[r], pBv = pB[r + 1], pC = pB[r + 2], pD = pB[r + 3];
        ACC2(dA, pA); ACC2(dB, pBv); ACC2(dC, pC); ACC2(dD, pD);
    }
    for (; r < nr; ++r) {
        int c = cB[r];
        unsigned d = *(const unsigned*)(xb + c);
        float4 p = pB[r];
        ACC2(d, p);
    }
#undef ACC2
    // ---- fold the two 32-lane halves (same dims, disjoint edges) -----------
    a0 += __shfl_xor(a0, 32, 64); a1 += __shfl_xor(a1, 32, 64);
    a2 += __shfl_xor(a2, 32, 64); a3 += __shfl_xor(a3, 32, 64);
    a4 += __shfl_xor(a4, 32, 64); a5 += __shfl_xor(a5, 32, 64);
    a6 += __shfl_xor(a6, 32, 64); a7 += __shfl_xor(a7, 32, 64);
    sp0 += __shfl_xor(sp0, 32, 64); sp1 += __shfl_xor(sp1, 32, 64);
    sp2 += __shfl_xor(sp2, 32, 64); sp3 += __shfl_xor(sp3, 32, 64);
    const float r0 = 1.f / sp0, r1 = 1.f / sp1;
    const float r2 = 1.f / sp2, r3 = 1.f / sp3;
    // ---- normalize + store s_cat[wid][h*64 + 2*l5] (dword per head) --------
    unsigned short* sr = s_cat + (size_t)wid * 256 + 2 * l5;
    unsigned w0 = (unsigned)f2h(a0 * r0) | ((unsigned)f2h(a1 * r0) << 16);
    unsigned w1 = (unsigned)f2h(a2 * r1) | ((unsigned)f2h(a3 * r1) << 16);
    unsigned w2 = (unsigned)f2h(a4 * r2) | ((unsigned)f2h(a5 * r2) << 16);
    unsigned w3 = (unsigned)f2h(a6 * r3) | ((unsigned)f2h(a7 * r3) << 16);
    *(unsigned*)(sr)       = w0;
    *(unsigned*)(sr + 64)  = w1;
    *(unsigned*)(sr + 128) = w2;
    *(unsigned*)(sr + 192) = w3;
}

// ---------------- post: out = relu(s_cat @ Wstack/4 + bias) . fc_w + fc_b ----
// Streaming MFMA GEMM [N,256]@[256,64] (mean folded into Bpost), fused epilogue.
template <typename T>
__device__ __forceinline__ void post_body(const unsigned short* __restrict__ s_cat,
                                          const unsigned short* __restrict__ Bpost,
                                          const T* __restrict__ bias,
                                          const T* __restrict__ fc_w,
                                          const T* __restrict__ fc_b,
                                          float* __restrict__ out) {
    const int tid = threadIdx.x;
    const int wav = tid >> 6, lane = tid & 63;
    const int quad = lane >> 4, r15 = lane & 15;
    const int m0 = blockIdx.x * 64;
    int gr = m0 + wav * 16 + r15;
    if (gr >= N_NODES) gr = N_NODES - 1;        // clamp; stores guarded
    const half8* arow = (const half8*)((const char*)s_cat + (size_t)gr * 512);
    half8 af[8];
#pragma unroll
    for (int kt = 0; kt < 8; ++kt) af[kt] = arow[kt * 4 + quad];
    f32x4 acc[4];
#pragma unroll
    for (int nt = 0; nt < 4; ++nt) acc[nt] = (f32x4){0.f, 0.f, 0.f, 0.f};
    const half8* bp = (const half8*)Bpost;
#pragma unroll
    for (int kt = 0; kt < 8; ++kt)
#pragma unroll
        for (int nt = 0; nt < 4; ++nt)
            acc[nt] = __builtin_amdgcn_mfma_f32_16x16x32_f16(
                af[kt], bp[(kt * 4 + nt) * 64 + lane], acc[nt], 0, 0, 0);
    float bi[4], fw[4];
#pragma unroll
    for (int nt = 0; nt < 4; ++nt) {
        int c = nt * 16 + r15;
        bi[nt] = cvt<T>(bias[c]);
        fw[nt] = cvt<T>(fc_w[c]);
    }
    const float fcb = cvt<T>(fc_b[0]);
#pragma unroll
    for (int r = 0; r < 4; ++r) {
        float p = 0.f;
#pragma unroll
        for (int nt = 0; nt < 4; ++nt) {
            float o = acc[nt][r] + bi[nt];
            o = o > 0.f ? o : 0.f;              // relu
            p = fmaf(o, fw[nt], p);
        }
#pragma unroll
        for (int off = 8; off > 0; off >>= 1) p += __shfl_xor(p, off, 64);
        int row = m0 + wav * 16 + quad * 4 + r;
        if (r15 == 0 && row < N_NODES) out[row] = p + fcb;
    }
}

__global__ __launch_bounds__(256) void k_post(const unsigned short* __restrict__ s_cat,
                                              const unsigned short* __restrict__ Bpost,
                                              const void* __restrict__ bias,
                                              const void* __restrict__ fc_w,
                                              const void* __restrict__ fc_b,
                                              const int* __restrict__ flags,
                                              float* __restrict__ out) {
    if (flags[1])
        post_body<float>(s_cat, Bpost, (const float*)bias, (const float*)fc_w,
                         (const float*)fc_b, out);
    else
        post_body<__hip_bfloat16>(s_cat, Bpost, (const __hip_bfloat16*)bias,
                                  (const __hip_bfloat16*)fc_w,
                                  (const __hip_bfloat16*)fc_b, out);
}

extern "C" void kernel_launch(void* const* d_in, const int* in_sizes, int n_in,
                              void* d_out, int out_size, void* d_ws, size_t ws_size,
                              hipStream_t stream) {
    const void* x       = d_in[0];
    const int*  ei      = (const int*)d_in[1];
    const void* W       = d_in[2];
    const void* att_src = d_in[3];
    const void* att_dst = d_in[4];
    const void* bias    = d_in[5];
    const void* fc_w    = d_in[6];
    const void* fc_b    = d_in[7];
    float* out = (float*)d_out;

    char* wsb = (char*)d_ws;                                     // ~40.3 MB total
    unsigned short* x16   = (unsigned short*)wsb;                // 6.4 MB (f16 x)
    unsigned short* s_cat = (unsigned short*)(wsb + 6400000);    // 25.6 MB
    unsigned* queue = (unsigned*)s_cat;          // 3.61 MB, ALIASES s_cat:
                                                 // k_scat reads it before k_agg writes
    unsigned short* Batt  = (unsigned short*)(wsb + 32000000);   // 2 KB
    unsigned short* Bpost = (unsigned short*)(wsb + 32002048);   // 32 KB
    float* a_src = (float*)(wsb + 32034816);                     // 800 KB
    float* a_dst = (float*)(wsb + 32834816);                     // 800 KB
    unsigned short* col_pad = (unsigned short*)(wsb + 33634816); // 6.4 MB
    int* flags = (int*)(wsb + 40034816);                         // 8 B
    int* qcnt  = (int*)(wsb + 40034824);                         // 784 B

    k_init<<<6, 256, 0, stream>>>((const unsigned*)x, ei, W, att_src,
                                  att_dst, qcnt, flags, Batt, Bpost);
    k_mid<<<NT, 256, 0, stream>>>(x, Batt, ei, flags, qcnt, queue,
                                  x16, a_src, a_dst);
    k_scat<<<NREG, 256, 0, stream>>>(queue, qcnt, col_pad);
    k_aggregate<<<((size_t)N_NODES * 64 + 255) / 256, 256, 0, stream>>>(
        col_pad, a_src, a_dst, x16, s_cat);
    k_post<<<NT, 256, 0, stream>>>(s_cat, Bpost, bias, fc_w, fc_b, flags, out);
}